// Round 3
// baseline (253.571 us; speedup 1.0000x reference)
//
#include <hip/hip_runtime.h>
#include <hip/hip_bf16.h>

#define HH 8
#define DKK 32
#define DM 256
#define NN 512
#define DE 40
#define DHID 32

__device__ __forceinline__ unsigned int pack_bf16x2(float a, float b) {
    union { __hip_bfloat16 h; unsigned short u; } ua, ub;
    ua.h = __float2bfloat16(a);
    ub.h = __float2bfloat16(b);
    return (unsigned int)ua.u | ((unsigned int)ub.u << 16);
}
__device__ __forceinline__ float bf16_bits_to_f(unsigned int u16) {
    return __uint_as_float(u16 << 16);
}

// ---------------- Q/K/V projection: 4 rows per block ----------------
__global__ __launch_bounds__(256) void proj_kernel(
    const float* __restrict__ query, const float* __restrict__ key_,
    const float* __restrict__ value,
    const float* __restrict__ Wq, const float* __restrict__ bq,
    const float* __restrict__ Wk, const float* __restrict__ bk,
    const float* __restrict__ Wv, const float* __restrict__ bv,
    float* __restrict__ Q, float* __restrict__ K, float* __restrict__ V)
{
    const int r0 = blockIdx.x * 4;
    const int c = threadIdx.x;
    float aq[4], ak[4], av[4];
    const float bqc = bq[c], bkc = bk[c], bvc = bv[c];
#pragma unroll
    for (int r = 0; r < 4; ++r) { aq[r] = bqc; ak[r] = bkc; av[r] = bvc; }
    for (int k = 0; k < DM; ++k) {
        const float wq = Wq[k*DM + c];
        const float wk = Wk[k*DM + c];
        const float wv = Wv[k*DM + c];
#pragma unroll
        for (int r = 0; r < 4; ++r) {
            aq[r] = fmaf(query[(size_t)(r0+r)*DM + k], wq, aq[r]);
            ak[r] = fmaf(key_ [(size_t)(r0+r)*DM + k], wk, ak[r]);
            av[r] = fmaf(value[(size_t)(r0+r)*DM + k], wv, av[r]);
        }
    }
#pragma unroll
    for (int r = 0; r < 4; ++r) {
        Q[(size_t)(r0+r)*DM + c] = aq[r];
        K[(size_t)(r0+r)*DM + c] = ak[r];
        V[(size_t)(r0+r)*DM + c] = av[r];
    }
}

// ---------------- fused relative attention: one block per (b,i) row ----------------
// Online-softmax over 2 chunks of 256 j. Edges read exactly once.
__global__ __launch_bounds__(256, 4) void attn_kernel(
    const float* __restrict__ edges, const int* __restrict__ mask,
    const float* __restrict__ rkW1, const float* __restrict__ rkb1,
    const float* __restrict__ rkW2, const float* __restrict__ rkb2,
    const float* __restrict__ rvW1, const float* __restrict__ rvb1,
    const float* __restrict__ rvW2, const float* __restrict__ rvb2,
    const float* __restrict__ vvec,
    const float* __restrict__ Wo, const float* __restrict__ bo,
    const float* __restrict__ Q, const float* __restrict__ K, const float* __restrict__ V,
    float* __restrict__ out)
{
    const int bi = blockIdx.x;          // b*512 + i
    const int b  = bi >> 9;
    const int i  = bi & 511;
    const int tid = threadIdx.x;
    const float inv = 0.17677669529663687f; // 1/sqrt(32)

    __shared__ __align__(16) float sc[HH*256];     // chunk scores -> exp(s-m)
    __shared__ unsigned int ch[256*17];            // chunk h1v, bf16x2 (16 dw + 1 pad)
    __shared__ __align__(16) float wf[DM];
    __shared__ __align__(16) float gKs[HH*DKK];    // stride 32 (broadcast reads only)
    __shared__ float c0Ks[HH];
    __shared__ __align__(16) float A_l[HH*DKK];
    __shared__ __align__(16) float o_l[DM];

    const size_t ebase = (size_t)b*DE*NN*NN + (size_t)i*NN;

    // ---- phase 0a: w = inv*(q+k) + v ----
    wf[tid] = inv*(Q[(size_t)bi*DM + tid] + K[(size_t)bi*DM + tid]) + vvec[tid];
    __syncthreads();

    // ---- phase 0b: gK[h,t] = sum_d rkW2[t, h*32+d]*w[h,d]; c0K[h] = rkb2[h,:].w[h,:] ----
    {
        const int h = tid >> 5, t = tid & 31;
        float acc = 0.f;
#pragma unroll
        for (int d4 = 0; d4 < DKK/4; ++d4) {
            const float4 w4 = *(const float4*)(rkW2 + (size_t)t*DM + h*DKK + d4*4);
            const float4 f4 = *(const float4*)(&wf[h*DKK + d4*4]);
            acc = fmaf(w4.x, f4.x, acc); acc = fmaf(w4.y, f4.y, acc);
            acc = fmaf(w4.z, f4.z, acc); acc = fmaf(w4.w, f4.w, acc);
        }
        gKs[h*DKK + t] = acc;
        if (tid < HH) {
            float a2 = 0.f;
#pragma unroll
            for (int d = 0; d < DKK; ++d)
                a2 = fmaf(rkb2[tid*DKK + d], wf[tid*DKK + d], a2);
            c0Ks[tid] = a2;
        }
    }
    __syncthreads();

    const int h = tid >> 5, l = tid & 31;   // group mapping, consistent for A and o
    float m_run = -3e38f, Zacc = 0.f, accA = 0.f, accO = 0.f;
    const float* vb = V + (size_t)b*NN*DM;
    const float* qrow = Q + (size_t)bi*DM;  // wave-uniform -> scalar loads

#pragma unroll 1
    for (int cc = 0; cc < 2; ++cc) {
        const int j = cc*256 + tid;
        // ---- edge MLP layer-1, both branches, this thread's j ----
        float h1k[DHID], h1v[DHID];
#pragma unroll
        for (int t = 0; t < DHID; ++t) { h1k[t] = rkb1[t]; h1v[t] = rvb1[t]; }
        {
            const float* ep = edges + ebase + j;
            for (int c = 0; c < DE; ++c) {
                const float e = ep[(size_t)c*NN*NN];
#pragma unroll
                for (int t = 0; t < DHID; ++t) {
                    h1k[t] = fmaf(e, rkW1[c*DHID + t], h1k[t]);   // uniform weights
                    h1v[t] = fmaf(e, rvW1[c*DHID + t], h1v[t]);
                }
            }
        }
#pragma unroll
        for (int t = 0; t < DHID; ++t) {
            h1k[t] = h1k[t] > 0.f ? h1k[t] : 0.1f*h1k[t];
            h1v[t] = h1v[t] > 0.f ? h1v[t] : 0.1f*h1v[t];
        }
        // ---- scores for 8 heads (this j) ----
        {
            const int mk = mask[b*NN + j];
            const float* kp = K + ((size_t)b*NN + j)*DM;
#pragma unroll
            for (int hh = 0; hh < HH; ++hh) {
                float r = c0Ks[hh];
                const float4* g4 = (const float4*)(gKs + hh*DKK);
#pragma unroll
                for (int t4 = 0; t4 < DKK/4; ++t4) {
                    const float4 g = g4[t4];
                    r = fmaf(g.x, h1k[t4*4+0], r); r = fmaf(g.y, h1k[t4*4+1], r);
                    r = fmaf(g.z, h1k[t4*4+2], r); r = fmaf(g.w, h1k[t4*4+3], r);
                }
                float a = 0.f;
#pragma unroll
                for (int c4 = 0; c4 < DKK/4; ++c4) {
                    const float4 q4 = *(const float4*)(qrow + hh*DKK + c4*4);
                    const float4 k4 = *(const float4*)(kp   + hh*DKK + c4*4);
                    a = fmaf(q4.x, k4.x, a); a = fmaf(q4.y, k4.y, a);
                    a = fmaf(q4.z, k4.z, a); a = fmaf(q4.w, k4.w, a);
                }
                float v0 = fmaf(inv, a, r);
                if (mk == 0) v0 = -1e12f;
                sc[hh*256 + tid] = v0;
            }
        }
        // stash h1v (bf16 packed)
#pragma unroll
        for (int t2 = 0; t2 < 16; ++t2)
            ch[tid*17 + t2] = pack_bf16x2(h1v[2*t2], h1v[2*t2+1]);
        __syncthreads();

        // ---- online softmax update (group h: lane l owns jj = l*8..l*8+7) ----
        {
            float4 sa = *(const float4*)(sc + h*256 + l*8);
            float4 sb = *(const float4*)(sc + h*256 + l*8 + 4);
            float mc = fmaxf(fmaxf(fmaxf(sa.x, sa.y), fmaxf(sa.z, sa.w)),
                             fmaxf(fmaxf(sb.x, sb.y), fmaxf(sb.z, sb.w)));
#pragma unroll
            for (int off = 16; off; off >>= 1) mc = fmaxf(mc, __shfl_xor(mc, off, 32));
            const float mnew = fmaxf(m_run, mc);
            const float scl = __expf(m_run - mnew);
            m_run = mnew;
            Zacc *= scl; accA *= scl; accO *= scl;
            float4 ea, eb;
            ea.x = __expf(sa.x - m_run); ea.y = __expf(sa.y - m_run);
            ea.z = __expf(sa.z - m_run); ea.w = __expf(sa.w - m_run);
            eb.x = __expf(sb.x - m_run); eb.y = __expf(sb.y - m_run);
            eb.z = __expf(sb.z - m_run); eb.w = __expf(sb.w - m_run);
            *(float4*)(sc + h*256 + l*8)     = ea;
            *(float4*)(sc + h*256 + l*8 + 4) = eb;
            float zc = (ea.x + ea.y) + (ea.z + ea.w) + (eb.x + eb.y) + (eb.z + eb.w);
#pragma unroll
            for (int off = 16; off; off >>= 1) zc += __shfl_xor(zc, off, 32);
            Zacc += zc;
            // exp'd row h written & read by this same wave -> no barrier needed
        }
        // ---- accumulate: accO (o channel = tid), accA (h,t = h,l) ----
        {
            const float* vcol = vb + (size_t)cc*256*DM + tid;
#pragma unroll 4
            for (int jj = 0; jj < 256; ++jj) {
                const float p = sc[h*256 + jj];                       // broadcast
                accO = fmaf(p, vcol[(size_t)jj*DM], accO);
                const unsigned int pk = ch[jj*17 + (l >> 1)];
                accA = fmaf(p, bf16_bits_to_f((l & 1) ? (pk >> 16) : (pk & 0xffffu)), accA);
            }
        }
        __syncthreads();   // before next chunk overwrites sc / ch
    }

    const float rz = 1.f / Zacc;
    A_l[h*DKK + l] = accA * rz;
    __syncthreads();

    // ---- o2 and merged o ----
    {
        float o2 = rvb2[tid];
#pragma unroll
        for (int t = 0; t < DHID; ++t)
            o2 = fmaf(A_l[h*DKK + t], rvW2[(size_t)t*DM + tid], o2);
        o_l[tid] = fmaf(accO, rz, o2);
    }
    __syncthreads();

    // ---- epilogue: out = o @ Wo + bo ----
    {
        float acc = bo[tid];
        for (int k = 0; k < DM; ++k)
            acc = fmaf(o_l[k], Wo[(size_t)k*DM + tid], acc);
        out[(size_t)bi*DM + tid] = acc;
    }
}

extern "C" void kernel_launch(void* const* d_in, const int* in_sizes, int n_in,
                              void* d_out, int out_size, void* d_ws, size_t ws_size,
                              hipStream_t stream) {
    const float* query = (const float*)d_in[0];
    const float* key_  = (const float*)d_in[1];
    const float* value = (const float*)d_in[2];
    const float* edges = (const float*)d_in[3];
    const int*   mask  = (const int*)d_in[4];
    const float* Wq = (const float*)d_in[5];
    const float* bq = (const float*)d_in[6];
    const float* Wk = (const float*)d_in[7];
    const float* bk = (const float*)d_in[8];
    const float* Wv = (const float*)d_in[9];
    const float* bv = (const float*)d_in[10];
    const float* Wo = (const float*)d_in[11];
    const float* bo = (const float*)d_in[12];
    const float* rkW1 = (const float*)d_in[13];
    const float* rkb1 = (const float*)d_in[14];
    const float* rkW2 = (const float*)d_in[15];
    const float* rkb2 = (const float*)d_in[16];
    const float* rvW1 = (const float*)d_in[17];
    const float* rvb1 = (const float*)d_in[18];
    const float* rvW2 = (const float*)d_in[19];
    const float* rvb2 = (const float*)d_in[20];
    // d_in[21] (u) is softmax-invariant -> unused
    const float* vvec = (const float*)d_in[22];

    const int rows = in_sizes[0] / DM;   // b*n = 1024
    float* Qw = (float*)d_ws;
    float* Kw = Qw + (size_t)rows*DM;
    float* Vw = Kw + (size_t)rows*DM;

    hipLaunchKernelGGL(proj_kernel, dim3(rows/4), dim3(256), 0, stream,
                       query, key_, value, Wq, bq, Wk, bk, Wv, bv, Qw, Kw, Vw);
    hipLaunchKernelGGL(attn_kernel, dim3(rows), dim3(256), 0, stream,
                       edges, mask, rkW1, rkb1, rkW2, rkb2, rvW1, rvb1, rvW2, rvb2,
                       vvec, Wo, bo, Qw, Kw, Vw, (float*)d_out);
}

// Round 4
// 227.722 us; speedup vs baseline: 1.1135x; 1.1135x over previous
//
#include <hip/hip_runtime.h>
#include <hip/hip_bf16.h>

#define HH 8
#define DKK 32
#define DM 256
#define NN 512
#define DE 40
#define DHID 32

__device__ __forceinline__ unsigned short f2bf(float x) {
    union { __hip_bfloat16 h; unsigned short u; } c;
    c.h = __float2bfloat16(x);
    return c.u;
}
__device__ __forceinline__ float bf_lo(unsigned int u) {  // low ushort -> float
    return __uint_as_float(u << 16);
}
__device__ __forceinline__ float bf_hi(unsigned int u) {  // high ushort -> float
    return __uint_as_float(u & 0xffff0000u);
}

// ---------------- Q/K/V projection: 4 rows (same batch) per block ----------------
// Writes Q row-major; K,V transposed [b][c][n] for coalesced j-access downstream.
__global__ __launch_bounds__(256) void proj_kernel(
    const float* __restrict__ query, const float* __restrict__ key_,
    const float* __restrict__ value,
    const float* __restrict__ Wq, const float* __restrict__ bq,
    const float* __restrict__ Wk, const float* __restrict__ bk,
    const float* __restrict__ Wv, const float* __restrict__ bv,
    float* __restrict__ Q, float* __restrict__ KT, float* __restrict__ VT)
{
    const int r0 = blockIdx.x * 4;          // global row (b*512 + n), 4-aligned
    const int c  = threadIdx.x;
    const int b  = r0 >> 9;
    const int n0 = r0 & 511;
    float aq[4], ak[4], av[4];
    const float bqc = bq[c], bkc = bk[c], bvc = bv[c];
#pragma unroll
    for (int r = 0; r < 4; ++r) { aq[r] = bqc; ak[r] = bkc; av[r] = bvc; }
    for (int k = 0; k < DM; ++k) {
        const float wq = Wq[k*DM + c];
        const float wk = Wk[k*DM + c];
        const float wv = Wv[k*DM + c];
#pragma unroll
        for (int r = 0; r < 4; ++r) {
            aq[r] = fmaf(query[(size_t)(r0+r)*DM + k], wq, aq[r]);   // uniform x
            ak[r] = fmaf(key_ [(size_t)(r0+r)*DM + k], wk, ak[r]);
            av[r] = fmaf(value[(size_t)(r0+r)*DM + k], wv, av[r]);
        }
    }
#pragma unroll
    for (int r = 0; r < 4; ++r) Q[(size_t)(r0+r)*DM + c] = aq[r];
    *(float4*)(KT + ((size_t)(b*DM + c))*NN + n0) = make_float4(ak[0], ak[1], ak[2], ak[3]);
    *(float4*)(VT + ((size_t)(b*DM + c))*NN + n0) = make_float4(av[0], av[1], av[2], av[3]);
}

// ---------------- fused relative attention: one block per (b,i) row ----------------
__global__ __launch_bounds__(256) void attn_kernel(
    const float* __restrict__ edges, const int* __restrict__ mask,
    const float* __restrict__ rkW1, const float* __restrict__ rkb1,
    const float* __restrict__ rkW2, const float* __restrict__ rkb2,
    const float* __restrict__ rvW1, const float* __restrict__ rvb1,
    const float* __restrict__ rvW2, const float* __restrict__ rvb2,
    const float* __restrict__ vvec,
    const float* __restrict__ Wo, const float* __restrict__ bo,
    const float* __restrict__ Q, const float* __restrict__ KT, const float* __restrict__ VT,
    float* __restrict__ out)
{
    const int bi = blockIdx.x;          // b*512 + i
    const int b  = bi >> 9;
    const int i  = bi & 511;
    const int tid = threadIdx.x;
    const int h = tid >> 5, l = tid & 31;
    const float inv = 0.17677669529663687f; // 1/sqrt(32)

    __shared__ __align__(16) float sc[HH*256];      // chunk scores -> exp(s-m)
    __shared__ unsigned short ch16[32*258];         // h1v^T bf16, stride 258 (129 dw ~ cf-free)
    __shared__ __align__(16) float wf[DM];
    __shared__ __align__(16) float gKs[HH*DKK];
    __shared__ float c0Ks[HH];
    __shared__ __align__(16) float A_l[HH*DKK];
    __shared__ __align__(16) float o_l[DM];

    const size_t ebase = (size_t)b*DE*NN*NN + (size_t)i*NN;
    const float* qrow = Q  + (size_t)bi*DM;          // wave-uniform -> scalar loads
    const float* ktb  = KT + (size_t)b*DM*NN;
    const float* vtb  = VT + (size_t)b*DM*NN;

    // ---- w = inv*(q+k) + v ----
    wf[tid] = inv*(qrow[tid] + ktb[(size_t)tid*NN + i]) + vvec[tid];
    __syncthreads();

    // ---- gK[h,t] = sum_d rkW2[t, h*32+d]*w[h,d]; c0K[h] = rkb2[h,:].w[h,:] ----
    {
        float acc = 0.f;
#pragma unroll
        for (int d4 = 0; d4 < DKK/4; ++d4) {
            const float4 w4 = *(const float4*)(rkW2 + (size_t)l*DM + h*DKK + d4*4);
            const float4 f4 = *(const float4*)(&wf[h*DKK + d4*4]);
            acc = fmaf(w4.x, f4.x, acc); acc = fmaf(w4.y, f4.y, acc);
            acc = fmaf(w4.z, f4.z, acc); acc = fmaf(w4.w, f4.w, acc);
        }
        gKs[h*DKK + l] = acc;
        if (tid < HH) {
            float a2 = 0.f;
#pragma unroll
            for (int d = 0; d < DKK; ++d)
                a2 = fmaf(rkb2[tid*DKK + d], wf[tid*DKK + d], a2);
            c0Ks[tid] = a2;
        }
    }
    __syncthreads();

    float m_run = -3e38f, Zacc = 0.f, accA = 0.f, accO = 0.f;

#pragma unroll 1
    for (int cc = 0; cc < 2; ++cc) {
        const int j = cc*256 + tid;
        // ---- edge MLP layer-1, both branches, this thread's j (staged loads) ----
        float h1k[DHID], h1v[DHID];
#pragma unroll
        for (int t = 0; t < DHID; ++t) { h1k[t] = rkb1[t]; h1v[t] = rvb1[t]; }
        {
            const float* ep = edges + ebase + j;
#pragma unroll 1
            for (int c0 = 0; c0 < DE; c0 += 10) {
                float ev[10];
#pragma unroll
                for (int u = 0; u < 10; ++u) ev[u] = ep[(size_t)(c0+u)*NN*NN];
#pragma unroll
                for (int u = 0; u < 10; ++u) {
                    const float* w1k = rkW1 + (c0+u)*DHID;   // uniform
                    const float* w1v = rvW1 + (c0+u)*DHID;
#pragma unroll
                    for (int t = 0; t < DHID; ++t) {
                        h1k[t] = fmaf(ev[u], w1k[t], h1k[t]);
                        h1v[t] = fmaf(ev[u], w1v[t], h1v[t]);
                    }
                }
            }
        }
#pragma unroll
        for (int t = 0; t < DHID; ++t) {
            h1k[t] = h1k[t] > 0.f ? h1k[t] : 0.1f*h1k[t];
            h1v[t] = h1v[t] > 0.f ? h1v[t] : 0.1f*h1v[t];
        }
        // stash h1v transposed (bf16), frees 32 regs before score loop
#pragma unroll
        for (int t = 0; t < DHID; ++t) ch16[t*258 + tid] = f2bf(h1v[t]);

        // ---- scores for 8 heads (this j), K via transposed coalesced loads ----
        {
            const int mk = mask[b*NN + j];
#pragma unroll
            for (int hh = 0; hh < HH; ++hh) {
                float r = c0Ks[hh];
                const float4* g4 = (const float4*)(gKs + hh*DKK);
#pragma unroll
                for (int t4 = 0; t4 < DKK/4; ++t4) {
                    const float4 g = g4[t4];
                    r = fmaf(g.x, h1k[t4*4+0], r); r = fmaf(g.y, h1k[t4*4+1], r);
                    r = fmaf(g.z, h1k[t4*4+2], r); r = fmaf(g.w, h1k[t4*4+3], r);
                }
                float a = 0.f;
#pragma unroll
                for (int d8 = 0; d8 < DKK; d8 += 8) {
                    float kd[8];
#pragma unroll
                    for (int u = 0; u < 8; ++u)
                        kd[u] = ktb[(size_t)(hh*DKK + d8 + u)*NN + j];   // coalesced
#pragma unroll
                    for (int u = 0; u < 8; ++u)
                        a = fmaf(qrow[hh*DKK + d8 + u], kd[u], a);       // uniform q
                }
                float v0 = fmaf(inv, a, r);
                if (mk == 0) v0 = -1e12f;
                sc[hh*256 + tid] = v0;
            }
        }
        __syncthreads();

        // ---- online softmax update (group h; lane l owns jj = 32k + l) ----
        {
            float sv[8];
            float mc = -3e38f;
#pragma unroll
            for (int k = 0; k < 8; ++k) {
                sv[k] = sc[h*256 + 32*k + l];
                mc = fmaxf(mc, sv[k]);
            }
#pragma unroll
            for (int off = 16; off; off >>= 1) mc = fmaxf(mc, __shfl_xor(mc, off, 32));
            const float mnew = fmaxf(m_run, mc);
            const float scl = __expf(m_run - mnew);
            m_run = mnew;
            Zacc *= scl; accA *= scl; accO *= scl;
            float zc = 0.f;
#pragma unroll
            for (int k = 0; k < 8; ++k) {
                const float e = __expf(sv[k] - m_run);
                sc[h*256 + 32*k + l] = e;
                zc += e;
            }
#pragma unroll
            for (int off = 16; off; off >>= 1) zc += __shfl_xor(zc, off, 32);
            Zacc += zc;
            // exp'd row h written & read by the same 32-lane group -> no barrier
        }

        // ---- accumulate: accO (channel tid over j), accA (h1v^T row l over j) ----
        {
            const float* vrow = vtb + (size_t)tid*NN + cc*256;
            const unsigned int* crow = (const unsigned int*)(ch16 + l*258);
            float aO0 = 0.f, aO1 = 0.f, aA0 = 0.f, aA1 = 0.f;
#pragma unroll 2
            for (int jj = 0; jj < 256; jj += 8) {
                const float4 p0 = *(const float4*)(sc + h*256 + jj);       // broadcast
                const float4 p1 = *(const float4*)(sc + h*256 + jj + 4);
                const float4 v0 = *(const float4*)(vrow + jj);
                const float4 v1 = *(const float4*)(vrow + jj + 4);
                const unsigned int c01 = crow[(jj>>1)+0];
                const unsigned int c23 = crow[(jj>>1)+1];
                const unsigned int c45 = crow[(jj>>1)+2];
                const unsigned int c67 = crow[(jj>>1)+3];
                aO0 = fmaf(p0.x, v0.x, aO0); aO0 = fmaf(p0.y, v0.y, aO0);
                aO0 = fmaf(p0.z, v0.z, aO0); aO0 = fmaf(p0.w, v0.w, aO0);
                aO1 = fmaf(p1.x, v1.x, aO1); aO1 = fmaf(p1.y, v1.y, aO1);
                aO1 = fmaf(p1.z, v1.z, aO1); aO1 = fmaf(p1.w, v1.w, aO1);
                aA0 = fmaf(p0.x, bf_lo(c01), aA0); aA0 = fmaf(p0.y, bf_hi(c01), aA0);
                aA0 = fmaf(p0.z, bf_lo(c23), aA0); aA0 = fmaf(p0.w, bf_hi(c23), aA0);
                aA1 = fmaf(p1.x, bf_lo(c45), aA1); aA1 = fmaf(p1.y, bf_hi(c45), aA1);
                aA1 = fmaf(p1.z, bf_lo(c67), aA1); aA1 = fmaf(p1.w, bf_hi(c67), aA1);
            }
            accO += aO0 + aO1;
            accA += aA0 + aA1;
        }
        __syncthreads();   // before next chunk overwrites sc / ch16
    }

    const float rz = 1.f / Zacc;
    A_l[h*DKK + l] = accA * rz;
    __syncthreads();

    // ---- o2 and merged o ----
    {
        float o2 = rvb2[tid];
#pragma unroll
        for (int t = 0; t < DHID; ++t)
            o2 = fmaf(A_l[h*DKK + t], rvW2[(size_t)t*DM + tid], o2);
        o_l[tid] = fmaf(accO, rz, o2);
    }
    __syncthreads();

    // ---- epilogue: out = o @ Wo + bo ----
    {
        float acc = bo[tid];
        for (int k = 0; k < DM; ++k)
            acc = fmaf(o_l[k], Wo[(size_t)k*DM + tid], acc);
        out[(size_t)bi*DM + tid] = acc;
    }
}

extern "C" void kernel_launch(void* const* d_in, const int* in_sizes, int n_in,
                              void* d_out, int out_size, void* d_ws, size_t ws_size,
                              hipStream_t stream) {
    const float* query = (const float*)d_in[0];
    const float* key_  = (const float*)d_in[1];
    const float* value = (const float*)d_in[2];
    const float* edges = (const float*)d_in[3];
    const int*   mask  = (const int*)d_in[4];
    const float* Wq = (const float*)d_in[5];
    const float* bq = (const float*)d_in[6];
    const float* Wk = (const float*)d_in[7];
    const float* bk = (const float*)d_in[8];
    const float* Wv = (const float*)d_in[9];
    const float* bv = (const float*)d_in[10];
    const float* Wo = (const float*)d_in[11];
    const float* bo = (const float*)d_in[12];
    const float* rkW1 = (const float*)d_in[13];
    const float* rkb1 = (const float*)d_in[14];
    const float* rkW2 = (const float*)d_in[15];
    const float* rkb2 = (const float*)d_in[16];
    const float* rvW1 = (const float*)d_in[17];
    const float* rvb1 = (const float*)d_in[18];
    const float* rvW2 = (const float*)d_in[19];
    const float* rvb2 = (const float*)d_in[20];
    // d_in[21] (u) is softmax-invariant -> unused
    const float* vvec = (const float*)d_in[22];

    const int rows = in_sizes[0] / DM;   // b*n = 1024
    float* Qw  = (float*)d_ws;
    float* KTw = Qw  + (size_t)rows*DM;
    float* VTw = KTw + (size_t)rows*DM;

    hipLaunchKernelGGL(proj_kernel, dim3(rows/4), dim3(256), 0, stream,
                       query, key_, value, Wq, bq, Wk, bk, Wv, bv, Qw, KTw, VTw);
    hipLaunchKernelGGL(attn_kernel, dim3(rows), dim3(256), 0, stream,
                       edges, mask, rkW1, rkb1, rkW2, rkb2, rvW1, rvb1, rvW2, rvb2,
                       vvec, Wo, bo, Qw, KTw, VTw, (float*)d_out);
}

// Round 5
// 136.896 us; speedup vs baseline: 1.8523x; 1.6635x over previous
//
#include <hip/hip_runtime.h>
#include <hip/hip_bf16.h>

#define HH 8
#define DKK 32
#define DM 256
#define NN 512
#define DE 40
#define DHID 32

__device__ __forceinline__ unsigned short f2bf(float x) {
    union { __hip_bfloat16 h; unsigned short u; } c;
    c.h = __float2bfloat16(x);
    return c.u;
}
__device__ __forceinline__ float bf_lo(unsigned int u) {
    return __uint_as_float(u << 16);
}
__device__ __forceinline__ float bf_hi(unsigned int u) {
    return __uint_as_float(u & 0xffff0000u);
}

// ---------------- Q/K/V projection: 4 rows per block (all row-major) ----------------
__global__ __launch_bounds__(256) void proj_kernel(
    const float* __restrict__ query, const float* __restrict__ key_,
    const float* __restrict__ value,
    const float* __restrict__ Wq, const float* __restrict__ bq,
    const float* __restrict__ Wk, const float* __restrict__ bk,
    const float* __restrict__ Wv, const float* __restrict__ bv,
    float* __restrict__ Q, float* __restrict__ K, float* __restrict__ V)
{
    const int r0 = blockIdx.x * 4;
    const int c = threadIdx.x;
    float aq[4], ak[4], av[4];
    const float bqc = bq[c], bkc = bk[c], bvc = bv[c];
#pragma unroll
    for (int r = 0; r < 4; ++r) { aq[r] = bqc; ak[r] = bkc; av[r] = bvc; }
    for (int k = 0; k < DM; ++k) {
        const float wq = Wq[k*DM + c];
        const float wk = Wk[k*DM + c];
        const float wv = Wv[k*DM + c];
#pragma unroll
        for (int r = 0; r < 4; ++r) {
            aq[r] = fmaf(query[(size_t)(r0+r)*DM + k], wq, aq[r]);   // uniform x
            ak[r] = fmaf(key_ [(size_t)(r0+r)*DM + k], wk, ak[r]);
            av[r] = fmaf(value[(size_t)(r0+r)*DM + k], wv, av[r]);
        }
    }
#pragma unroll
    for (int r = 0; r < 4; ++r) {
        Q[(size_t)(r0+r)*DM + c] = aq[r];
        K[(size_t)(r0+r)*DM + c] = ak[r];
        V[(size_t)(r0+r)*DM + c] = av[r];
    }
}

// ---------------- s1[b,h,i,j] = inv * q_h(i) . k_h(j) : 64x64 tile per block ----------------
__global__ __launch_bounds__(256) void s1_kernel(
    const float* __restrict__ Q, const float* __restrict__ K, float* __restrict__ s1)
{
    const int tid = threadIdx.x;
    const int bh = blockIdx.y, b = bh >> 3, hh = bh & 7;
    const int ti = (blockIdx.x >> 3) * 64, tj = (blockIdx.x & 7) * 64;
    __shared__ float Qt[64][33];
    __shared__ float Kt[64][33];
    const int c = tid & 31, r0 = tid >> 5;
#pragma unroll
    for (int s = 0; s < 8; ++s) {
        Qt[r0 + 8*s][c] = Q[(size_t)(b*NN + ti + r0 + 8*s)*DM + hh*DKK + c];
        Kt[r0 + 8*s][c] = K[(size_t)(b*NN + tj + r0 + 8*s)*DM + hh*DKK + c];
    }
    __syncthreads();
    const int tx = tid & 15, ty = tid >> 4;
    float acc[4][4] = {};
#pragma unroll
    for (int k = 0; k < DKK; ++k) {
        float qv[4], kv[4];
#pragma unroll
        for (int u = 0; u < 4; ++u) { qv[u] = Qt[ty*4+u][k]; kv[u] = Kt[tx*4+u][k]; }
#pragma unroll
        for (int ri = 0; ri < 4; ++ri)
#pragma unroll
            for (int cj = 0; cj < 4; ++cj)
                acc[ri][cj] = fmaf(qv[ri], kv[cj], acc[ri][cj]);
    }
    const float inv = 0.17677669529663687f;
#pragma unroll
    for (int ri = 0; ri < 4; ++ri) {
        float4 o = make_float4(acc[ri][0]*inv, acc[ri][1]*inv, acc[ri][2]*inv, acc[ri][3]*inv);
        *(float4*)(s1 + ((size_t)(b*HH + hh)*NN + ti + ty*4 + ri)*NN + tj + tx*4) = o;
    }
}

// ---------------- fused relative attention: one block per (b,i) row ----------------
__global__ __launch_bounds__(256) void attn_kernel(
    const float* __restrict__ edges, const int* __restrict__ mask,
    const float* __restrict__ rkW1, const float* __restrict__ rkb1,
    const float* __restrict__ rkW2, const float* __restrict__ rkb2,
    const float* __restrict__ rvW1, const float* __restrict__ rvb1,
    const float* __restrict__ rvW2, const float* __restrict__ rvb2,
    const float* __restrict__ vvec,
    const float* __restrict__ Wo, const float* __restrict__ bo,
    const float* __restrict__ Q, const float* __restrict__ K, const float* __restrict__ V,
    const float* __restrict__ s1w,
    float* __restrict__ out)
{
    const int bi = blockIdx.x;          // b*512 + i
    const int b  = bi >> 9;
    const int i  = bi & 511;
    const int tid = threadIdx.x;
    const int h = tid >> 5, l = tid & 31;       // head-group mapping (softmax, accA)
    const int team = tid >> 6, qq = tid & 63;   // team mapping (accO): channels qq*4..+3
    const int hq = qq >> 3;                     // head of those channels
    const float inv = 0.17677669529663687f;

    __shared__ __align__(16) float sc[HH*260];      // chunk scores -> exp (stride 260)
    __shared__ unsigned short ch16[32*258];         // h1v^T bf16 (row t, stride 258)
    __shared__ __align__(16) float wf[DM];
    __shared__ __align__(16) float gKs[HH*DKK];
    __shared__ float c0Ks[HH];
    __shared__ __align__(16) float A_l[HH*DKK];
    __shared__ __align__(16) float po[4*DM];        // per-team accO partials
    __shared__ __align__(16) float o_l[DM];
    __shared__ float scl_s[HH], zfin_s[HH];

    const size_t ebase = (size_t)b*DE*NN*NN + (size_t)i*NN;
    const float* qrow = Q + (size_t)bi*DM;

    // ---- w = inv*(q+k) + v ----
    wf[tid] = inv*(qrow[tid] + K[(size_t)bi*DM + tid]) + vvec[tid];
    __syncthreads();

    // ---- gK[h,t] = rkW2[t, h*32:].w[h,:]; c0K[h] = rkb2[h,:].w[h,:] ----
    {
        float acc = 0.f;
#pragma unroll
        for (int d4 = 0; d4 < DKK/4; ++d4) {
            const float4 w4 = *(const float4*)(rkW2 + (size_t)l*DM + h*DKK + d4*4);
            const float4 f4 = *(const float4*)(&wf[h*DKK + d4*4]);
            acc = fmaf(w4.x, f4.x, acc); acc = fmaf(w4.y, f4.y, acc);
            acc = fmaf(w4.z, f4.z, acc); acc = fmaf(w4.w, f4.w, acc);
        }
        gKs[h*DKK + l] = acc;
        if (tid < HH) {
            float a2 = 0.f;
#pragma unroll
            for (int d = 0; d < DKK; ++d)
                a2 = fmaf(rkb2[tid*DKK + d], wf[tid*DKK + d], a2);
            c0Ks[tid] = a2;
        }
    }
    __syncthreads();

    float m_run = -3e38f, Zacc = 0.f, accA = 0.f;
    float aO0 = 0.f, aO1 = 0.f, aO2 = 0.f, aO3 = 0.f;
    const float* vb  = V + (size_t)b*NN*DM;
    const float* s1b = s1w + (size_t)b*HH*NN*NN + (size_t)i*NN;

#pragma unroll 1
    for (int cc = 0; cc < 2; ++cc) {
        const int j = cc*256 + tid;
        // ---- edge MLP layer-1, both branches, this thread's j (staged loads) ----
        float h1k[DHID], h1v[DHID];
#pragma unroll
        for (int t = 0; t < DHID; ++t) { h1k[t] = rkb1[t]; h1v[t] = rvb1[t]; }
        {
            const float* ep = edges + ebase + j;
#pragma unroll 1
            for (int c0 = 0; c0 < DE; c0 += 10) {
                float ev[10];
#pragma unroll
                for (int u = 0; u < 10; ++u) ev[u] = ep[(size_t)(c0+u)*NN*NN];
#pragma unroll
                for (int u = 0; u < 10; ++u) {
                    const float* w1k = rkW1 + (c0+u)*DHID;   // uniform
                    const float* w1v = rvW1 + (c0+u)*DHID;
#pragma unroll
                    for (int t = 0; t < DHID; ++t) {
                        h1k[t] = fmaf(ev[u], w1k[t], h1k[t]);
                        h1v[t] = fmaf(ev[u], w1v[t], h1v[t]);
                    }
                }
            }
        }
#pragma unroll
        for (int t = 0; t < DHID; ++t) {
            h1k[t] = h1k[t] > 0.f ? h1k[t] : 0.1f*h1k[t];
            h1v[t] = h1v[t] > 0.f ? h1v[t] : 0.1f*h1v[t];
        }
#pragma unroll
        for (int t = 0; t < DHID; ++t) ch16[t*258 + tid] = f2bf(h1v[t]);

        // ---- scores: s2 (gK.h1k) + precomputed s1, mask ----
        {
            const int mk = mask[b*NN + j];
#pragma unroll
            for (int hh = 0; hh < HH; ++hh) {
                float r = c0Ks[hh];
                const float4* g4 = (const float4*)(gKs + hh*DKK);
#pragma unroll
                for (int t4 = 0; t4 < DKK/4; ++t4) {
                    const float4 g = g4[t4];
                    r = fmaf(g.x, h1k[t4*4+0], r); r = fmaf(g.y, h1k[t4*4+1], r);
                    r = fmaf(g.z, h1k[t4*4+2], r); r = fmaf(g.w, h1k[t4*4+3], r);
                }
                r += s1b[(size_t)hh*NN*NN + j];               // coalesced
                if (mk == 0) r = -1e12f;
                sc[hh*260 + tid] = r;
            }
        }
        __syncthreads();

        // ---- online softmax (group h), publish scl ----
        {
            float sv[8];
            float mc = -3e38f;
#pragma unroll
            for (int k = 0; k < 8; ++k) {
                sv[k] = sc[h*260 + 32*k + l];
                mc = fmaxf(mc, sv[k]);
            }
#pragma unroll
            for (int off = 16; off; off >>= 1) mc = fmaxf(mc, __shfl_xor(mc, off, 32));
            const float mnew = fmaxf(m_run, mc);
            const float scl = __expf(m_run - mnew);
            m_run = mnew;
            Zacc *= scl; accA *= scl;
            float zc = 0.f;
#pragma unroll
            for (int k = 0; k < 8; ++k) {
                const float e = __expf(sv[k] - m_run);
                sc[h*260 + 32*k + l] = e;
                zc += e;
            }
#pragma unroll
            for (int off = 16; off; off >>= 1) zc += __shfl_xor(zc, off, 32);
            Zacc += zc;
            if (l == 0) scl_s[h] = scl;
        }
        __syncthreads();

        // ---- accO (team mapping, float4 coalesced V) + accA (bf16 LDS) ----
        {
            const float s4 = scl_s[hq];
            aO0 *= s4; aO1 *= s4; aO2 *= s4; aO3 *= s4;
            const float* vrow = vb + (size_t)(cc*256 + team)*DM + qq*4;
#pragma unroll 4
            for (int it = 0; it < 64; ++it) {
                const float p = sc[hq*260 + team + 4*it];      // broadcast per 8 lanes
                const float4 v4 = *(const float4*)(vrow + (size_t)it*4*DM);
                aO0 = fmaf(p, v4.x, aO0); aO1 = fmaf(p, v4.y, aO1);
                aO2 = fmaf(p, v4.z, aO2); aO3 = fmaf(p, v4.w, aO3);
            }
            const unsigned int* crow = (const unsigned int*)ch16 + l*129;
            float aA0 = 0.f, aA1 = 0.f;
#pragma unroll 2
            for (int jj = 0; jj < 256; jj += 8) {
                const float4 p0 = *(const float4*)(sc + h*260 + jj);
                const float4 p1 = *(const float4*)(sc + h*260 + jj + 4);
                const unsigned int c01 = crow[(jj>>1)+0];
                const unsigned int c23 = crow[(jj>>1)+1];
                const unsigned int c45 = crow[(jj>>1)+2];
                const unsigned int c67 = crow[(jj>>1)+3];
                aA0 = fmaf(p0.x, bf_lo(c01), aA0); aA0 = fmaf(p0.y, bf_hi(c01), aA0);
                aA0 = fmaf(p0.z, bf_lo(c23), aA0); aA0 = fmaf(p0.w, bf_hi(c23), aA0);
                aA1 = fmaf(p1.x, bf_lo(c45), aA1); aA1 = fmaf(p1.y, bf_hi(c45), aA1);
                aA1 = fmaf(p1.z, bf_lo(c67), aA1); aA1 = fmaf(p1.w, bf_hi(c67), aA1);
            }
            accA += aA0 + aA1;
        }
        __syncthreads();
    }

    if (l == 0) zfin_s[h] = Zacc;
    A_l[h*DKK + l] = accA / Zacc;
    __syncthreads();

    // ---- publish team accO partials (normalized) ----
    {
        const float rz = 1.f / zfin_s[hq];
        *(float4*)(po + team*DM + qq*4) = make_float4(aO0*rz, aO1*rz, aO2*rz, aO3*rz);
    }
    __syncthreads();

    // ---- o = sum(team partials) + o2 ----
    {
        float o1 = po[0*DM + tid] + po[1*DM + tid] + po[2*DM + tid] + po[3*DM + tid];
        float o2 = rvb2[tid];
#pragma unroll
        for (int t = 0; t < DHID; ++t)
            o2 = fmaf(A_l[h*DKK + t], rvW2[(size_t)t*DM + tid], o2);
        o_l[tid] = o1 + o2;
    }
    __syncthreads();

    // ---- epilogue: out = o @ Wo + bo ----
    {
        float acc = bo[tid];
#pragma unroll 4
        for (int k = 0; k < DM; ++k)
            acc = fmaf(o_l[k], Wo[(size_t)k*DM + tid], acc);
        out[(size_t)bi*DM + tid] = acc;
    }
}

extern "C" void kernel_launch(void* const* d_in, const int* in_sizes, int n_in,
                              void* d_out, int out_size, void* d_ws, size_t ws_size,
                              hipStream_t stream) {
    const float* query = (const float*)d_in[0];
    const float* key_  = (const float*)d_in[1];
    const float* value = (const float*)d_in[2];
    const float* edges = (const float*)d_in[3];
    const int*   mask  = (const int*)d_in[4];
    const float* Wq = (const float*)d_in[5];
    const float* bq = (const float*)d_in[6];
    const float* Wk = (const float*)d_in[7];
    const float* bk = (const float*)d_in[8];
    const float* Wv = (const float*)d_in[9];
    const float* bv = (const float*)d_in[10];
    const float* Wo = (const float*)d_in[11];
    const float* bo = (const float*)d_in[12];
    const float* rkW1 = (const float*)d_in[13];
    const float* rkb1 = (const float*)d_in[14];
    const float* rkW2 = (const float*)d_in[15];
    const float* rkb2 = (const float*)d_in[16];
    const float* rvW1 = (const float*)d_in[17];
    const float* rvb1 = (const float*)d_in[18];
    const float* rvW2 = (const float*)d_in[19];
    const float* rvb2 = (const float*)d_in[20];
    // d_in[21] (u) is softmax-invariant -> unused
    const float* vvec = (const float*)d_in[22];

    const int rows = in_sizes[0] / DM;   // b*n = 1024
    float* Qw  = (float*)d_ws;
    float* Kw  = Qw + (size_t)rows*DM;
    float* Vw  = Kw + (size_t)rows*DM;
    float* s1w = Vw + (size_t)rows*DM;   // 2*8*512*512 fp32 = 16 MB

    hipLaunchKernelGGL(proj_kernel, dim3(rows/4), dim3(256), 0, stream,
                       query, key_, value, Wq, bq, Wk, bk, Wv, bv, Qw, Kw, Vw);
    hipLaunchKernelGGL(s1_kernel, dim3(64, 16), dim3(256), 0, stream,
                       Qw, Kw, s1w);
    hipLaunchKernelGGL(attn_kernel, dim3(rows), dim3(256), 0, stream,
                       edges, mask, rkW1, rkb1, rkW2, rkb2, rvW1, rvb1, rvW2, rvb2,
                       vvec, Wo, bo, Qw, Kw, Vw, s1w, (float*)d_out);
}